// Round 4
// baseline (213.120 us; speedup 1.0000x reference)
//
#include <hip/hip_runtime.h>

#define B 16
#define C 128
#define NN 1024
#define KV 512
#define CHO 4

typedef _Float16 f16x8 __attribute__((ext_vector_type(8)));
typedef float f32x4 __attribute__((ext_vector_type(4)));

__device__ __forceinline__ unsigned short f2h(float v) {
  _Float16 h = (_Float16)v;
  return __builtin_bit_cast(unsigned short, h);
}
__device__ __forceinline__ unsigned int packh2(float a, float b) {
  return (unsigned int)f2h(a) | ((unsigned int)f2h(b) << 16);
}
__device__ __forceinline__ f16x8 ldcvt8(const float* __restrict__ p) {
  float4 a = *reinterpret_cast<const float4*>(p);
  float4 b = *reinterpret_cast<const float4*>(p + 4);
  f16x8 r;
  r[0] = (_Float16)a.x; r[1] = (_Float16)a.y; r[2] = (_Float16)a.z; r[3] = (_Float16)a.w;
  r[4] = (_Float16)b.x; r[5] = (_Float16)b.y; r[6] = (_Float16)b.z; r[7] = (_Float16)b.w;
  return r;
}

// ---------------- K1: projections via f16 MFMA
// fT[b][n][c'] = (Wq x)^T   gT[b][m][c'] = (Wk x)^T   hv[b][k][n] = Wv x
// Block: 64 out-rows (rt) x 64 n (nt). rt 0-3 -> fT/gT (transposed store,
// A=W B=XT); rt 4-11 -> hv (direct store, A=XT B=Wv).
__global__ __launch_bounds__(256, 4) void proj_kernel(
    const float* __restrict__ x, const float* __restrict__ Wq,
    const float* __restrict__ Wk, const float* __restrict__ Wv,
    unsigned short* __restrict__ fT, unsigned short* __restrict__ gT,
    unsigned short* __restrict__ hv)
{
  int wg = blockIdx.x;
  wg = (wg & 7) * 384 + (wg >> 3);      // XCD cluster: 3072 = 8*384 (2 batches/XCD-chunk)
  const int b   = wg / 192;
  const int rem = wg % 192;
  const int rt  = rem % 12;
  const int n0  = (rem / 12) * 64;

  __shared__ __align__(16) unsigned short XT[64][136];   // XT[n][c] f16

  const int t = threadIdx.x;
  const int w = t >> 6, l = t & 63, lg = l >> 4, lm = l & 15;

  // stage XT (transpose + f16 convert)
  {
    const float* xb = x + (size_t)b * C * NN;
    #pragma unroll
    for (int i = 0; i < 8; ++i) {
      int flat = t + i * 256;          // 0..2047
      int c  = flat >> 4;              // 0..127
      int ng = flat & 15;              // n-group of 4
      float4 v = *reinterpret_cast<const float4*>(xb + (size_t)c * NN + n0 + ng * 4);
      XT[ng * 4 + 0][c] = f2h(v.x);
      XT[ng * 4 + 1][c] = f2h(v.y);
      XT[ng * 4 + 2][c] = f2h(v.z);
      XT[ng * 4 + 3][c] = f2h(v.w);
    }
  }
  __syncthreads();

  if (rt < 4) {
    // D[r][n]: A = W rows, B = XT cols. lane: col=lm -> n, row=4lg+reg -> c'
    const float* Wsrc = (rt < 2) ? Wq : Wk;
    unsigned short* dst = (rt < 2) ? fT : gT;
    const int c0 = (rt & 1) * 64;
    const int r  = c0 + 16 * w + lm;
    f16x8 af[4];
    #pragma unroll
    for (int c4 = 0; c4 < 4; ++c4)
      af[c4] = ldcvt8(Wsrc + (size_t)r * C + c4 * 32 + lg * 8);
    #pragma unroll
    for (int nt4 = 0; nt4 < 4; ++nt4) {
      f32x4 acc = {0.f, 0.f, 0.f, 0.f};
      #pragma unroll
      for (int c4 = 0; c4 < 4; ++c4) {
        f16x8 xb = *reinterpret_cast<const f16x8*>(&XT[16 * nt4 + lm][c4 * 32 + lg * 8]);
        acc = __builtin_amdgcn_mfma_f32_16x16x32_f16(af[c4], xb, acc, 0, 0, 0);
      }
      int n = n0 + 16 * nt4 + lm;
      ushort4 o = { f2h(acc[0]), f2h(acc[1]), f2h(acc[2]), f2h(acc[3]) };
      *reinterpret_cast<ushort4*>(dst + ((size_t)(b * NN) + n) * C + c0 + 16 * w + 4 * lg) = o;
    }
  } else {
    // D[n][k]: A = XT rows, B = Wv cols. lane: col=lm -> k (own kk), row -> n
    const int kk = (rt - 4) * 64 + 16 * w + lm;
    f16x8 wb[4];
    #pragma unroll
    for (int c4 = 0; c4 < 4; ++c4)
      wb[c4] = ldcvt8(Wv + (size_t)kk * C + c4 * 32 + lg * 8);
    #pragma unroll
    for (int nt4 = 0; nt4 < 4; ++nt4) {
      f32x4 acc = {0.f, 0.f, 0.f, 0.f};
      #pragma unroll
      for (int c4 = 0; c4 < 4; ++c4) {
        f16x8 xa = *reinterpret_cast<const f16x8*>(&XT[16 * nt4 + lm][c4 * 32 + lg * 8]);
        acc = __builtin_amdgcn_mfma_f32_16x16x32_f16(xa, wb[c4], acc, 0, 0, 0);
      }
      ushort4 o = { f2h(acc[0]), f2h(acc[1]), f2h(acc[2]), f2h(acc[3]) };
      *reinterpret_cast<ushort4*>(hv + ((size_t)(b * KV) + kk) * NN + n0 + 16 * nt4 + 4 * lg) = o;
    }
  }
}

// ---------------- K2: MFMA flash attention, 8 waves, k-split 64/wave
// Block: 32 m-cols, 8 waves. Wave w: k-range [64w,64w+64); QK duty m-sub = w&1
// (parity waves duplicate QK+softmax; only w<2 write P/resc/lsum to LDS).
__global__ __launch_bounds__(512, 4) void attn_kernel(
    const unsigned short* __restrict__ fT, const unsigned short* __restrict__ gT,
    const unsigned short* __restrict__ hv, const float* __restrict__ gamma,
    const float* __restrict__ mask, float* __restrict__ out)
{
  int wg = blockIdx.x;
  wg = (wg & 7) * 64 + (wg >> 3);       // XCD cluster: 512 = 8*64 (2 batches/XCD-chunk)
  const int b  = wg >> 5;
  const int m0 = (wg & 31) * 32;

  const int t = threadIdx.x;
  const int w = t >> 6, l = t & 63, lg = l >> 4, lm = l & 15;
  const int ms = w & 1;

  __shared__ __align__(16) unsigned short P_lds[32][40];  // [m][n] f16
  __shared__ float resc_s[32];
  __shared__ float lsum_s[32];

  // Q frags: B operand, lane holds gT[m0+16ms+lm][c4*32 + 8lg + i]
  f16x8 qf[4];
  {
    const unsigned short* qp = gT + ((size_t)(b * NN) + m0 + 16 * ms + lm) * C + lg * 8;
    #pragma unroll
    for (int c4 = 0; c4 < 4; ++c4)
      qf[c4] = *reinterpret_cast<const f16x8*>(qp + c4 * 32);
  }

  f32x4 acc[4][2];  // [kt][mt]: k = 64w+16kt+4lg+reg, m = m0+16mt+lm
  #pragma unroll
  for (int kt = 0; kt < 4; ++kt) {
    acc[kt][0] = (f32x4){0.f, 0.f, 0.f, 0.f};
    acc[kt][1] = (f32x4){0.f, 0.f, 0.f, 0.f};
  }

  float M = -3.0e38f, Lpart = 0.f;

  const unsigned short* kp = fT + ((size_t)(b * NN) + lm) * C + lg * 8;
  const unsigned short* vp = hv + ((size_t)(b * KV) + 64 * w + lm) * NN + lg * 8;

  #pragma unroll 1
  for (int n0 = 0; n0 < NN; n0 += 32) {
    // V frags early
    f16x8 vf[4];
    #pragma unroll
    for (int kt = 0; kt < 4; ++kt)
      vf[kt] = *reinterpret_cast<const f16x8*>(vp + (size_t)(16 * kt) * NN + n0);

    // QK^T (swapped): D[n][m-sub]
    f32x4 st0 = {0.f, 0.f, 0.f, 0.f}, st1 = {0.f, 0.f, 0.f, 0.f};
    #pragma unroll
    for (int c4 = 0; c4 < 4; ++c4) {
      f16x8 k0 = *reinterpret_cast<const f16x8*>(kp + (size_t)(n0)      * C + c4 * 32);
      f16x8 k1 = *reinterpret_cast<const f16x8*>(kp + (size_t)(n0 + 16) * C + c4 * 32);
      st0 = __builtin_amdgcn_mfma_f32_16x16x32_f16(k0, qf[c4], st0, 0, 0, 0);
      st1 = __builtin_amdgcn_mfma_f32_16x16x32_f16(k1, qf[c4], st1, 0, 0, 0);
    }

    // online softmax over n (lane holds n = n0 + {0,16} + 4lg + reg of col m0+16ms+lm)
    float cmax = fmaxf(fmaxf(fmaxf(st0.x, st0.y), fmaxf(st0.z, st0.w)),
                       fmaxf(fmaxf(st1.x, st1.y), fmaxf(st1.z, st1.w)));
    cmax = fmaxf(cmax, __shfl_xor(cmax, 16, 64));
    cmax = fmaxf(cmax, __shfl_xor(cmax, 32, 64));
    float r = 1.0f;
    if (!__all(cmax <= M + 8.0f)) {       // T13 defer-rescale
      float newM = fmaxf(M, cmax);
      r = __expf(M - newM);
      M = newM;
      Lpart *= r;
    }
    float p0 = __expf(st0.x - M), p1 = __expf(st0.y - M),
          p2 = __expf(st0.z - M), p3 = __expf(st0.w - M),
          p4 = __expf(st1.x - M), p5 = __expf(st1.y - M),
          p6 = __expf(st1.z - M), p7 = __expf(st1.w - M);
    Lpart += ((p0 + p1) + (p2 + p3)) + ((p4 + p5) + (p6 + p7));
    if (w < 2) {
      if (lg == 0) resc_s[16 * w + lm] = r;
      unsigned short* prow = &P_lds[16 * w + lm][0];
      *(unsigned int*)(prow + 4 * lg)          = packh2(p0, p1);
      *(unsigned int*)(prow + 4 * lg + 2)      = packh2(p2, p3);
      *(unsigned int*)(prow + 16 + 4 * lg)     = packh2(p4, p5);
      *(unsigned int*)(prow + 16 + 4 * lg + 2) = packh2(p6, p7);
    }
    __syncthreads();

    // rescale accumulators (rare: T13)
    float rr0 = resc_s[lm], rr1 = resc_s[16 + lm];
    if (!__all((rr0 == 1.f) & (rr1 == 1.f))) {
      #pragma unroll
      for (int kt = 0; kt < 4; ++kt) {
        acc[kt][0] *= rr0;
        acc[kt][1] *= rr1;
      }
    }

    // P^T B-frags
    f16x8 pt0 = *reinterpret_cast<const f16x8*>(&P_lds[lm][8 * lg]);
    f16x8 pt1 = *reinterpret_cast<const f16x8*>(&P_lds[16 + lm][8 * lg]);

    // PV: D[k][m]
    #pragma unroll
    for (int kt = 0; kt < 4; ++kt) {
      acc[kt][0] = __builtin_amdgcn_mfma_f32_16x16x32_f16(vf[kt], pt0, acc[kt][0], 0, 0, 0);
      acc[kt][1] = __builtin_amdgcn_mfma_f32_16x16x32_f16(vf[kt], pt1, acc[kt][1], 0, 0, 0);
    }
    __syncthreads();
  }

  // denominators
  float Lp = Lpart;
  Lp += __shfl_xor(Lp, 16, 64);
  Lp += __shfl_xor(Lp, 32, 64);
  if (w < 2 && lg == 0) lsum_s[16 * w + lm] = Lp;
  __syncthreads();

  const float gam = gamma[0];
  const float scv0 = gam / lsum_s[lm];
  const float scv1 = gam / lsum_s[16 + lm];

  // out[b][oc][m][ch] + mask[oc][m][ch];  k = 64w+16kt+4lg+reg, oc=k&127, ch=k>>7
  #pragma unroll
  for (int kt = 0; kt < 4; ++kt) {
    #pragma unroll
    for (int mt = 0; mt < 2; ++mt) {
      float sc = mt ? scv1 : scv0;
      int m = m0 + 16 * mt + lm;
      #pragma unroll
      for (int reg = 0; reg < 4; ++reg) {
        int k  = 64 * w + 16 * kt + 4 * lg + reg;
        int oc = k & 127, ch = k >> 7;
        float v = acc[kt][mt][reg] * sc + mask[((size_t)oc * NN + m) * CHO + ch];
        out[(((size_t)(b * 128 + oc)) * NN + m) * CHO + ch] = v;
      }
    }
  }
}

extern "C" void kernel_launch(void* const* d_in, const int* in_sizes, int n_in,
                              void* d_out, int out_size, void* d_ws, size_t ws_size,
                              hipStream_t stream) {
  const float* x     = (const float*)d_in[0];
  const float* Wq    = (const float*)d_in[1];
  const float* Wk    = (const float*)d_in[2];
  const float* Wv    = (const float*)d_in[3];
  const float* gamma = (const float*)d_in[4];
  const float* mask  = (const float*)d_in[5];
  float* out = (float*)d_out;

  unsigned short* fT = (unsigned short*)d_ws;                 // [B][NN][C]  f16
  unsigned short* gT = fT + (size_t)B * NN * C;               // [B][NN][C]  f16
  unsigned short* hv = gT + (size_t)B * NN * C;               // [B][KV][NN] f16

  proj_kernel<<<dim3(3072), 256, 0, stream>>>(x, Wq, Wk, Wv, fT, gT, hv);
  attn_kernel<<<dim3(512), 512, 0, stream>>>(fT, gT, hv, gamma, mask, out);
}

// Round 5
// 103.533 us; speedup vs baseline: 2.0585x; 2.0585x over previous
//
#include <hip/hip_runtime.h>

#define B 16
#define C 128
#define NN 1024
#define KV 512
#define CHO 4

typedef _Float16 f16x8 __attribute__((ext_vector_type(8)));
typedef float f32x4 __attribute__((ext_vector_type(4)));

__device__ __forceinline__ unsigned short f2h(float v) {
  _Float16 h = (_Float16)v;
  return __builtin_bit_cast(unsigned short, h);
}
__device__ __forceinline__ unsigned int packh2(float a, float b) {
  return (unsigned int)f2h(a) | ((unsigned int)f2h(b) << 16);
}
__device__ __forceinline__ f16x8 ldcvt8(const float* __restrict__ p) {
  float4 a = *reinterpret_cast<const float4*>(p);
  float4 b = *reinterpret_cast<const float4*>(p + 4);
  f16x8 r;
  r[0] = (_Float16)a.x; r[1] = (_Float16)a.y; r[2] = (_Float16)a.z; r[3] = (_Float16)a.w;
  r[4] = (_Float16)b.x; r[5] = (_Float16)b.y; r[6] = (_Float16)b.z; r[7] = (_Float16)b.w;
  return r;
}

// ---------------- K1: projections via f16 MFMA (unchanged from R4; verified)
__global__ __launch_bounds__(256, 4) void proj_kernel(
    const float* __restrict__ x, const float* __restrict__ Wq,
    const float* __restrict__ Wk, const float* __restrict__ Wv,
    unsigned short* __restrict__ fT, unsigned short* __restrict__ gT,
    unsigned short* __restrict__ hv)
{
  int wg = blockIdx.x;
  wg = (wg & 7) * 384 + (wg >> 3);      // XCD cluster
  const int b   = wg / 192;
  const int rem = wg % 192;
  const int rt  = rem % 12;
  const int n0  = (rem / 12) * 64;

  __shared__ __align__(16) unsigned short XT[64][136];   // XT[n][c] f16

  const int t = threadIdx.x;
  const int w = t >> 6, l = t & 63, lg = l >> 4, lm = l & 15;

  {
    const float* xb = x + (size_t)b * C * NN;
    #pragma unroll
    for (int i = 0; i < 8; ++i) {
      int flat = t + i * 256;
      int c  = flat >> 4;
      int ng = flat & 15;
      float4 v = *reinterpret_cast<const float4*>(xb + (size_t)c * NN + n0 + ng * 4);
      XT[ng * 4 + 0][c] = f2h(v.x);
      XT[ng * 4 + 1][c] = f2h(v.y);
      XT[ng * 4 + 2][c] = f2h(v.z);
      XT[ng * 4 + 3][c] = f2h(v.w);
    }
  }
  __syncthreads();

  if (rt < 4) {
    const float* Wsrc = (rt < 2) ? Wq : Wk;
    unsigned short* dst = (rt < 2) ? fT : gT;
    const int c0 = (rt & 1) * 64;
    const int r  = c0 + 16 * w + lm;
    f16x8 af[4];
    #pragma unroll
    for (int c4 = 0; c4 < 4; ++c4)
      af[c4] = ldcvt8(Wsrc + (size_t)r * C + c4 * 32 + lg * 8);
    #pragma unroll
    for (int nt4 = 0; nt4 < 4; ++nt4) {
      f32x4 acc = {0.f, 0.f, 0.f, 0.f};
      #pragma unroll
      for (int c4 = 0; c4 < 4; ++c4) {
        f16x8 xb = *reinterpret_cast<const f16x8*>(&XT[16 * nt4 + lm][c4 * 32 + lg * 8]);
        acc = __builtin_amdgcn_mfma_f32_16x16x32_f16(af[c4], xb, acc, 0, 0, 0);
      }
      int n = n0 + 16 * nt4 + lm;
      ushort4 o = { f2h(acc[0]), f2h(acc[1]), f2h(acc[2]), f2h(acc[3]) };
      *reinterpret_cast<ushort4*>(dst + ((size_t)(b * NN) + n) * C + c0 + 16 * w + 4 * lg) = o;
    }
  } else {
    const int kk = (rt - 4) * 64 + 16 * w + lm;
    f16x8 wb[4];
    #pragma unroll
    for (int c4 = 0; c4 < 4; ++c4)
      wb[c4] = ldcvt8(Wv + (size_t)kk * C + c4 * 32 + lg * 8);
    #pragma unroll
    for (int nt4 = 0; nt4 < 4; ++nt4) {
      f32x4 acc = {0.f, 0.f, 0.f, 0.f};
      #pragma unroll
      for (int c4 = 0; c4 < 4; ++c4) {
        f16x8 xa = *reinterpret_cast<const f16x8*>(&XT[16 * nt4 + lm][c4 * 32 + lg * 8]);
        acc = __builtin_amdgcn_mfma_f32_16x16x32_f16(xa, wb[c4], acc, 0, 0, 0);
      }
      ushort4 o = { f2h(acc[0]), f2h(acc[1]), f2h(acc[2]), f2h(acc[3]) };
      *reinterpret_cast<ushort4*>(hv + ((size_t)(b * KV) + kk) * NN + n0 + 16 * nt4 + 4 * lg) = o;
    }
  }
}

// ---------------- K2: MFMA flash attention (R3 structure, 64-n chunks,
// single barrier/chunk via parity double-buffered P/resc)
// Block: 64 m-cols, 4 waves. Wave w: softmax owner of m-sub w AND PV owner of
// k-range [128w, 128w+128).
__global__ __launch_bounds__(256, 1) void attn_kernel(
    const unsigned short* __restrict__ fT, const unsigned short* __restrict__ gT,
    const unsigned short* __restrict__ hv, const float* __restrict__ gamma,
    const float* __restrict__ mask, float* __restrict__ out)
{
  int wg = blockIdx.x;
  wg = (wg & 7) * 32 + (wg >> 3);       // XCD cluster: 2 batches per XCD chunk
  const int b  = wg >> 4;
  const int m0 = (wg & 15) * 64;

  const int t = threadIdx.x;
  const int w = t >> 6, l = t & 63, lg = l >> 4, lm = l & 15;

  // 72 cols: row stride 144B, 144/16=9 (odd) -> 16B reads spread uniformly
  __shared__ __align__(16) unsigned short P_lds[2][64][72];  // [par][m][n] f16
  __shared__ float resc_s[2][64];
  __shared__ float lsum_s[64];

  // Q frags: B operand, lane holds gT[m0+16w+lm][c4*32 + 8lg + i]
  f16x8 qf[4];
  {
    const unsigned short* qp = gT + ((size_t)(b * NN) + m0 + 16 * w + lm) * C + lg * 8;
    #pragma unroll
    for (int c4 = 0; c4 < 4; ++c4)
      qf[c4] = *reinterpret_cast<const f16x8*>(qp + c4 * 32);
  }

  f32x4 acc[8][4];  // [kt][mt]: k = 128w+16kt+4lg+reg, m = m0+16mt+lm
  #pragma unroll
  for (int kt = 0; kt < 8; ++kt)
    #pragma unroll
    for (int mt = 0; mt < 4; ++mt)
      acc[kt][mt] = (f32x4){0.f, 0.f, 0.f, 0.f};

  float M = -3.0e38f, Lpart = 0.f;

  const unsigned short* kp = fT + ((size_t)(b * NN) + lm) * C + lg * 8;
  const unsigned short* vp = hv + ((size_t)(b * KV) + 128 * w + lm) * NN + lg * 8;

  #pragma unroll 1
  for (int it = 0; it < 16; ++it) {
    const int n0  = it * 64;
    const int cur = it & 1;

    // V frags early (16 x 16B; consumed at end of chunk)
    f16x8 vf[8][2];
    #pragma unroll
    for (int kt = 0; kt < 8; ++kt) {
      vf[kt][0] = *reinterpret_cast<const f16x8*>(vp + (size_t)(16 * kt) * NN + n0);
      vf[kt][1] = *reinterpret_cast<const f16x8*>(vp + (size_t)(16 * kt) * NN + n0 + 32);
    }

    // QK^T (swapped): D[n][m-sub], 4 independent chains of 4
    f32x4 st[4];
    #pragma unroll
    for (int j = 0; j < 4; ++j) st[j] = (f32x4){0.f, 0.f, 0.f, 0.f};
    #pragma unroll
    for (int c4 = 0; c4 < 4; ++c4) {
      #pragma unroll
      for (int j = 0; j < 4; ++j) {
        f16x8 kf = *reinterpret_cast<const f16x8*>(kp + (size_t)(n0 + 16 * j) * C + c4 * 32);
        st[j] = __builtin_amdgcn_mfma_f32_16x16x32_f16(kf, qf[c4], st[j], 0, 0, 0);
      }
    }

    // online softmax over n (lane holds n = n0 + 16j + 4lg + reg, col m0+16w+lm)
    float cmax = -3.0e38f;
    #pragma unroll
    for (int j = 0; j < 4; ++j)
      cmax = fmaxf(cmax, fmaxf(fmaxf(st[j][0], st[j][1]), fmaxf(st[j][2], st[j][3])));
    cmax = fmaxf(cmax, __shfl_xor(cmax, 16, 64));
    cmax = fmaxf(cmax, __shfl_xor(cmax, 32, 64));
    float r = 1.0f;
    if (!__all(cmax <= M + 8.0f)) {       // T13 defer-rescale
      float newM = fmaxf(M, cmax);
      r = __expf(M - newM);
      M = newM;
      Lpart *= r;
    }
    float p[16];
    float ls = 0.f;
    #pragma unroll
    for (int j = 0; j < 4; ++j) {
      p[4 * j + 0] = __expf(st[j][0] - M);
      p[4 * j + 1] = __expf(st[j][1] - M);
      p[4 * j + 2] = __expf(st[j][2] - M);
      p[4 * j + 3] = __expf(st[j][3] - M);
      ls += (p[4 * j] + p[4 * j + 1]) + (p[4 * j + 2] + p[4 * j + 3]);
    }
    Lpart += ls;
    if (lg == 0) resc_s[cur][16 * w + lm] = r;
    {
      unsigned short* prow = &P_lds[cur][16 * w + lm][0];
      #pragma unroll
      for (int j = 0; j < 4; ++j) {
        *(unsigned int*)(prow + 16 * j + 4 * lg)     = packh2(p[4 * j],     p[4 * j + 1]);
        *(unsigned int*)(prow + 16 * j + 4 * lg + 2) = packh2(p[4 * j + 2], p[4 * j + 3]);
      }
    }
    __syncthreads();   // the ONLY barrier per chunk

    // rescale accumulators (rare: T13)
    float rr0 = resc_s[cur][lm],      rr1 = resc_s[cur][16 + lm],
          rr2 = resc_s[cur][32 + lm], rr3 = resc_s[cur][48 + lm];
    if (!__all((rr0 == 1.f) & (rr1 == 1.f) & (rr2 == 1.f) & (rr3 == 1.f))) {
      #pragma unroll
      for (int kt = 0; kt < 8; ++kt) {
        acc[kt][0] *= rr0; acc[kt][1] *= rr1;
        acc[kt][2] *= rr2; acc[kt][3] *= rr3;
      }
    }

    // P^T B-frags: lane holds P_lds[cur][16mt+lm][32h + 8lg + i]
    f16x8 pt[4][2];
    #pragma unroll
    for (int mt = 0; mt < 4; ++mt) {
      pt[mt][0] = *reinterpret_cast<const f16x8*>(&P_lds[cur][16 * mt + lm][8 * lg]);
      pt[mt][1] = *reinterpret_cast<const f16x8*>(&P_lds[cur][16 * mt + lm][32 + 8 * lg]);
    }

    // PV: D[k][m], 64 MFMA
    #pragma unroll
    for (int kt = 0; kt < 8; ++kt) {
      #pragma unroll
      for (int mt = 0; mt < 4; ++mt) {
        acc[kt][mt] = __builtin_amdgcn_mfma_f32_16x16x32_f16(vf[kt][0], pt[mt][0], acc[kt][mt], 0, 0, 0);
        acc[kt][mt] = __builtin_amdgcn_mfma_f32_16x16x32_f16(vf[kt][1], pt[mt][1], acc[kt][mt], 0, 0, 0);
      }
    }
    // no trailing barrier: next chunk writes the OTHER parity buffers
  }

  // denominators
  float Lp = Lpart;
  Lp += __shfl_xor(Lp, 16, 64);
  Lp += __shfl_xor(Lp, 32, 64);
  __syncthreads();
  if (lg == 0) lsum_s[16 * w + lm] = Lp;
  __syncthreads();

  const float gam = gamma[0];
  float scv[4] = { gam / lsum_s[lm],      gam / lsum_s[16 + lm],
                   gam / lsum_s[32 + lm], gam / lsum_s[48 + lm] };

  // out[b][oc][m][ch] + mask[oc][m][ch];  k = 128w+16kt+4lg+reg -> oc = k&127, ch = w
  #pragma unroll
  for (int kt = 0; kt < 8; ++kt) {
    #pragma unroll
    for (int mt = 0; mt < 4; ++mt) {
      int m = m0 + 16 * mt + lm;
      #pragma unroll
      for (int reg = 0; reg < 4; ++reg) {
        int oc = 16 * kt + 4 * lg + reg;
        float v = acc[kt][mt][reg] * scv[mt] + mask[((size_t)oc * NN + m) * CHO + w];
        out[(((size_t)(b * 128 + oc)) * NN + m) * CHO + w] = v;
      }
    }
  }
}

extern "C" void kernel_launch(void* const* d_in, const int* in_sizes, int n_in,
                              void* d_out, int out_size, void* d_ws, size_t ws_size,
                              hipStream_t stream) {
  const float* x     = (const float*)d_in[0];
  const float* Wq    = (const float*)d_in[1];
  const float* Wk    = (const float*)d_in[2];
  const float* Wv    = (const float*)d_in[3];
  const float* gamma = (const float*)d_in[4];
  const float* mask  = (const float*)d_in[5];
  float* out = (float*)d_out;

  unsigned short* fT = (unsigned short*)d_ws;                 // [B][NN][C]  f16
  unsigned short* gT = fT + (size_t)B * NN * C;               // [B][NN][C]  f16
  unsigned short* hv = gT + (size_t)B * NN * C;               // [B][KV][NN] f16

  proj_kernel<<<dim3(3072), 256, 0, stream>>>(x, Wq, Wk, Wv, fT, gT, hv);
  attn_kernel<<<dim3(256), 256, 0, stream>>>(fT, gT, hv, gamma, mask, out);
}